// Round 1
// baseline (843.945 us; speedup 1.0000x reference)
//
#include <hip/hip_runtime.h>

typedef unsigned short u16;
typedef short short8 __attribute__((ext_vector_type(8)));
typedef float f32x4 __attribute__((ext_vector_type(4)));
typedef unsigned short u16x4 __attribute__((ext_vector_type(4)));

__device__ __forceinline__ u16 f2bf(float f) {
  unsigned u = __builtin_bit_cast(unsigned, f);
  u += 0x7fffu + ((u >> 16) & 1u);
  return (u16)(u >> 16);
}
__device__ __forceinline__ float bf2f(u16 s) {
  unsigned u = ((unsigned)s) << 16;
  return __builtin_bit_cast(float, u);
}

#define GLDS16(gp, lp)                                                         \
  __builtin_amdgcn_global_load_lds(                                            \
      (__attribute__((address_space(1))) void*)(gp),                           \
      (__attribute__((address_space(3))) void*)(lp), 16, 0, 0)

// ---------------- cast fp32 -> bf16 ----------------
__global__ __launch_bounds__(256) void cast_bf16_k(const float* __restrict__ in,
                                                   u16* __restrict__ out, int n4) {
  int i = blockIdx.x * 256 + threadIdx.x;
  if (i >= n4) return;
  float4 v = ((const float4*)in)[i];
  u16x4 o = { f2bf(v.x), f2bf(v.y), f2bf(v.z), f2bf(v.w) };
  ((u16x4*)out)[i] = o;
}

// ---------------- weight transpose+cast: Wt[n][k] = W[k][n] ----------------
__global__ __launch_bounds__(256) void transw_k(const float* W0, const float* W1,
                                                const float* W2, const float* W3,
                                                const float* W4, const float* W5,
                                                u16* __restrict__ Wt) {
  int z = blockIdx.z;
  const float* W = z == 0 ? W0 : z == 1 ? W1 : z == 2 ? W2 : z == 3 ? W3 : z == 4 ? W4 : W5;
  u16* T = Wt + (size_t)z * 2048 * 2048;
  __shared__ float tile[64][65];
  int k0 = blockIdx.x * 64, n0 = blockIdx.y * 64;
  int c4 = (threadIdx.x & 15) * 4;
  int r = threadIdx.x >> 4;  // 0..15
#pragma unroll
  for (int i = 0; i < 4; ++i) {
    int row = r + i * 16;
    float4 v = *(const float4*)(W + (size_t)(k0 + row) * 2048 + n0 + c4);
    tile[row][c4 + 0] = v.x; tile[row][c4 + 1] = v.y;
    tile[row][c4 + 2] = v.z; tile[row][c4 + 3] = v.w;
  }
  __syncthreads();
#pragma unroll
  for (int i = 0; i < 4; ++i) {
    int nrow = r + i * 16;
    u16x4 o = { f2bf(tile[c4 + 0][nrow]), f2bf(tile[c4 + 1][nrow]),
                f2bf(tile[c4 + 2][nrow]), f2bf(tile[c4 + 3][nrow]) };
    *(u16x4*)(T + (size_t)(n0 + nrow) * 2048 + k0 + c4) = o;
  }
}

// ---------------- GEMM: out = A(MxK) * Wt(NxK)^T + bias ----------------
// K = N = 2048 fixed. mode 0: bf16 out[m*ldo+n]; mode 1: bf16 out[n*ldo+m]
// (for V^T); mode 2: fp32 out[m*ldo+n].
struct GemmJob {
  const u16* A; const u16* Bt; const float* bias; void* out;
  int M; int mode; int ldo;
};
struct GemmJobs { GemmJob j[8]; };

__global__ __launch_bounds__(256) void gemm_k(GemmJobs jobs) {
  GemmJob J = jobs.j[blockIdx.z];
  const int m0 = blockIdx.x * 128;
  if (m0 >= J.M) return;
  const int n0 = blockIdx.y * 128;
  __shared__ u16 Asm[128 * 32];
  __shared__ u16 Bsm[128 * 32];
  const int tid = threadIdx.x;
  const int lane = tid & 63;
  const int l15 = lane & 15, quad = lane >> 4;
  const int wave = tid >> 6;
  const int wr = (wave >> 1) * 64, wc = (wave & 1) * 64;
  f32x4 acc[4][4] = {};
  const int g0 = tid, g1 = tid + 256;
  const u16* ag0 = J.A + (size_t)(m0 + (g0 >> 2)) * 2048 + (g0 & 3) * 8;
  const u16* ag1 = J.A + (size_t)(m0 + (g1 >> 2)) * 2048 + (g1 & 3) * 8;
  const u16* bg0 = J.Bt + (size_t)(n0 + (g0 >> 2)) * 2048 + (g0 & 3) * 8;
  const u16* bg1 = J.Bt + (size_t)(n0 + (g1 >> 2)) * 2048 + (g1 & 3) * 8;
  u16* al0 = Asm + g0 * 8; u16* al1 = Asm + g1 * 8;
  u16* bl0 = Bsm + g0 * 8; u16* bl1 = Bsm + g1 * 8;
  for (int k0 = 0; k0 < 2048; k0 += 32) {
    GLDS16(ag0 + k0, al0);
    GLDS16(ag1 + k0, al1);
    GLDS16(bg0 + k0, bl0);
    GLDS16(bg1 + k0, bl1);
    __syncthreads();
    short8 af[4], bf[4];
#pragma unroll
    for (int mi = 0; mi < 4; ++mi)
      af[mi] = *(const short8*)(Asm + (wr + mi * 16 + l15) * 32 + quad * 8);
#pragma unroll
    for (int ni = 0; ni < 4; ++ni)
      bf[ni] = *(const short8*)(Bsm + (wc + ni * 16 + l15) * 32 + quad * 8);
#pragma unroll
    for (int mi = 0; mi < 4; ++mi)
#pragma unroll
      for (int ni = 0; ni < 4; ++ni)
        acc[mi][ni] = __builtin_amdgcn_mfma_f32_16x16x32_bf16(af[mi], bf[ni], acc[mi][ni], 0, 0, 0);
    __syncthreads();
  }
#pragma unroll
  for (int mi = 0; mi < 4; ++mi) {
#pragma unroll
    for (int ni = 0; ni < 4; ++ni) {
      int nn = n0 + wc + ni * 16 + l15;
      float bv = J.bias[nn];
#pragma unroll
      for (int r = 0; r < 4; ++r) {
        int mm = m0 + wr + mi * 16 + quad * 4 + r;
        if (mm >= J.M) continue;
        float v = acc[mi][ni][r] + bv;
        if (J.mode == 0)      ((u16*)J.out)[(size_t)mm * J.ldo + nn] = f2bf(v);
        else if (J.mode == 1) ((u16*)J.out)[(size_t)nn * J.ldo + mm] = f2bf(v);
        else                  ((float*)J.out)[(size_t)mm * J.ldo + nn] = v;
      }
    }
  }
}

// ---------------- RMSNorm in place (rows of 2048 bf16) ----------------
__global__ __launch_bounds__(256) void rmsnorm_k(u16* __restrict__ buf,
                                                 const float* __restrict__ g) {
  const int row = blockIdx.x, tid = threadIdx.x;
  u16* p = buf + (size_t)row * 2048 + tid * 8;
  short8 v = *(short8*)p;
  float x[8]; float s = 0.f;
#pragma unroll
  for (int i = 0; i < 8; ++i) { x[i] = bf2f((u16)v[i]); s += x[i] * x[i]; }
#pragma unroll
  for (int o = 1; o < 64; o <<= 1) s += __shfl_xor(s, o, 64);
  __shared__ float ws4[4];
  if ((tid & 63) == 0) ws4[tid >> 6] = s;
  __syncthreads();
  float tot = ws4[0] + ws4[1] + ws4[2] + ws4[3];
  float scale = rsqrtf(tot * (1.0f / 2048.0f) + 1e-6f);
  const float* gp = g + tid * 8;
  short8 o8;
#pragma unroll
  for (int i = 0; i < 8; ++i) o8[i] = (short)f2bf(x[i] * scale * gp[i]);
  *(short8*)p = o8;
}

// ---------------- flash attention (two softmax phases, summed) ----------------
// Q: (B,4096,2048) bf16; Kt: (B,512,2048); Vt: (B,16,128,512) = V^T;
// Ki: (B,288,2048) (257 valid); Vi: (B,16,128,288). out: (B,4096,2048) bf16.
__global__ __launch_bounds__(256) void attn_k(const u16* __restrict__ Q,
                                              const u16* __restrict__ Kt,
                                              const u16* __restrict__ Vt,
                                              const u16* __restrict__ Ki,
                                              const u16* __restrict__ Vi,
                                              const int* __restrict__ lens,
                                              u16* __restrict__ out) {
  const int b = blockIdx.z, h = blockIdx.y;
  const int tid = threadIdx.x, lane = tid & 63, wave = tid >> 6;
  const int l15 = lane & 15, quad = lane >> 4;
  const int m0 = blockIdx.x * 64 + wave * 16;  // q row within batch
  const float scale = 0.08838834764831845f;    // 1/sqrt(128)
  const float NEGINF = -__builtin_inff();
  __shared__ u16 pl[4][16][32];

  short8 qf[4];
  const u16* qb = Q + ((size_t)(b * 4096 + m0 + l15)) * 2048 + h * 128 + quad * 8;
#pragma unroll
  for (int kc = 0; kc < 4; ++kc) qf[kc] = *(const short8*)(qb + kc * 32);

  f32x4 otot[8];
  float run_m[4], run_l[4];
  f32x4 accv[8];

  auto phase = [&](const u16* Kb, const u16* Vb, int Lv, int ldv, bool first) {
#pragma unroll
    for (int r = 0; r < 4; ++r) { run_m[r] = NEGINF; run_l[r] = 0.f; }
#pragma unroll
    for (int dt = 0; dt < 8; ++dt)
#pragma unroll
      for (int r = 0; r < 4; ++r) accv[dt][r] = 0.f;
    const int ntiles = (Lv + 31) >> 5;
    for (int t = 0; t < ntiles; ++t) {
      const int kv0 = t * 32;
      f32x4 s0, s1;
#pragma unroll
      for (int r = 0; r < 4; ++r) { s0[r] = 0.f; s1[r] = 0.f; }
#pragma unroll
      for (int kc = 0; kc < 4; ++kc) {
        short8 kf0 = *(const short8*)(Kb + (size_t)(kv0 + l15) * 2048 + kc * 32 + quad * 8);
        short8 kf1 = *(const short8*)(Kb + (size_t)(kv0 + 16 + l15) * 2048 + kc * 32 + quad * 8);
        s0 = __builtin_amdgcn_mfma_f32_16x16x32_bf16(qf[kc], kf0, s0, 0, 0, 0);
        s1 = __builtin_amdgcn_mfma_f32_16x16x32_bf16(qf[kc], kf1, s1, 0, 0, 0);
      }
      const bool v0 = (kv0 + l15) < Lv, v1 = (kv0 + 16 + l15) < Lv;
      float al[4];
#pragma unroll
      for (int r = 0; r < 4; ++r) {
        s0[r] = v0 ? s0[r] * scale : NEGINF;
        s1[r] = v1 ? s1[r] * scale : NEGINF;
        float mx = fmaxf(s0[r], s1[r]);
#pragma unroll
        for (int o = 1; o < 16; o <<= 1) mx = fmaxf(mx, __shfl_xor(mx, o, 64));
        float nm = fmaxf(run_m[r], mx);
        al[r] = __expf(run_m[r] - nm);
        run_m[r] = nm;
        s0[r] = __expf(s0[r] - nm);
        s1[r] = __expf(s1[r] - nm);
        float sm = s0[r] + s1[r];
#pragma unroll
        for (int o = 1; o < 16; o <<= 1) sm += __shfl_xor(sm, o, 64);
        run_l[r] = run_l[r] * al[r] + sm;
        pl[wave][quad * 4 + r][l15] = f2bf(s0[r]);
        pl[wave][quad * 4 + r][16 + l15] = f2bf(s1[r]);
      }
#pragma unroll
      for (int dt = 0; dt < 8; ++dt)
#pragma unroll
        for (int r = 0; r < 4; ++r) accv[dt][r] *= al[r];
      short8 pf = *(const short8*)&pl[wave][l15][quad * 8];
#pragma unroll
      for (int dt = 0; dt < 8; ++dt) {
        short8 vf = *(const short8*)(Vb + (size_t)(dt * 16 + l15) * ldv + kv0 + quad * 8);
        accv[dt] = __builtin_amdgcn_mfma_f32_16x16x32_bf16(pf, vf, accv[dt], 0, 0, 0);
      }
    }
#pragma unroll
    for (int dt = 0; dt < 8; ++dt)
#pragma unroll
      for (int r = 0; r < 4; ++r) {
        float v = accv[dt][r] / run_l[r];
        if (first) otot[dt][r] = v; else otot[dt][r] += v;
      }
  };

  const u16* Kb_i = Ki + (size_t)(b * 288) * 2048 + h * 128;
  const u16* Vb_i = Vi + ((size_t)(b * 16 + h) * 128) * 288;
  phase(Kb_i, Vb_i, 257, 288, true);
  const u16* Kb_t = Kt + (size_t)(b * 512) * 2048 + h * 128;
  const u16* Vb_t = Vt + ((size_t)(b * 16 + h) * 128) * 512;
  phase(Kb_t, Vb_t, lens[b], 512, false);

  u16* ob = out + ((size_t)(b * 4096 + m0 + quad * 4)) * 2048 + h * 128 + l15;
#pragma unroll
  for (int dt = 0; dt < 8; ++dt)
#pragma unroll
    for (int r = 0; r < 4; ++r)
      ob[(size_t)r * 2048 + dt * 16] = f2bf(otot[dt][r]);
}

extern "C" void kernel_launch(void* const* d_in, const int* in_sizes, int n_in,
                              void* d_out, int out_size, void* d_ws, size_t ws_size,
                              hipStream_t stream) {
  const float* x   = (const float*)d_in[0];
  const float* ctx = (const float*)d_in[1];
  const int* lens  = (const int*)d_in[2];
  const float* Wq  = (const float*)d_in[3];
  const float* bq  = (const float*)d_in[4];
  const float* gq  = (const float*)d_in[5];
  const float* Wk  = (const float*)d_in[6];
  const float* bk  = (const float*)d_in[7];
  const float* gk  = (const float*)d_in[8];
  const float* Wv  = (const float*)d_in[9];
  const float* bv  = (const float*)d_in[10];
  const float* Wki = (const float*)d_in[11];
  const float* bki = (const float*)d_in[12];
  const float* gki = (const float*)d_in[13];
  const float* Wvi = (const float*)d_in[14];
  const float* bvi = (const float*)d_in[15];
  const float* Wo  = (const float*)d_in[16];
  const float* bo  = (const float*)d_in[17];
  float* out = (float*)d_out;

  char* p = (char*)d_ws;
  u16* x_bf   = (u16*)p; p += (size_t)8192 * 2048 * 2;     // also reused as attn_out
  u16* ctx_bf = (u16*)p; p += (size_t)2 * 769 * 2048 * 2;
  u16* Wt     = (u16*)p; p += (size_t)6 * 2048 * 2048 * 2; // [q,k,v,ki,vi,o] transposed bf16
  u16* Qb     = (u16*)p; p += (size_t)8192 * 2048 * 2;
  u16* Ktxt   = (u16*)p; p += (size_t)2 * 512 * 2048 * 2;
  u16* Vtt    = (u16*)p; p += (size_t)2 * 16 * 128 * 512 * 2;
  u16* Kimg   = (u16*)p; p += (size_t)2 * 288 * 2048 * 2;
  u16* Vti    = (u16*)p; p += (size_t)2 * 16 * 128 * 288 * 2;
  u16* attn_o = x_bf;

  cast_bf16_k<<<16384, 256, 0, stream>>>(x, x_bf, 8192 * 2048 / 4);
  cast_bf16_k<<<3076, 256, 0, stream>>>(ctx, ctx_bf, 2 * 769 * 2048 / 4);
  transw_k<<<dim3(32, 32, 6), 256, 0, stream>>>(Wq, Wk, Wv, Wki, Wvi, Wo, Wt);

  GemmJobs jq = {};
  jq.j[0] = { x_bf, Wt + 0ull * 4194304, bq, Qb, 8192, 0, 2048 };
  gemm_k<<<dim3(64, 16, 1), 256, 0, stream>>>(jq);

  GemmJobs jc = {};
  for (int b = 0; b < 2; ++b) {
    const u16* txtA = ctx_bf + (size_t)(b * 769 + 257) * 2048;
    const u16* imgA = ctx_bf + (size_t)(b * 769) * 2048;
    jc.j[0 + b] = { txtA, Wt + 1ull * 4194304, bk,  Ktxt + (size_t)b * 512 * 2048, 512, 0, 2048 };
    jc.j[2 + b] = { txtA, Wt + 2ull * 4194304, bv,  Vtt  + (size_t)b * 2048 * 512, 512, 1, 512 };
    jc.j[4 + b] = { imgA, Wt + 3ull * 4194304, bki, Kimg + (size_t)b * 288 * 2048, 257, 0, 2048 };
    jc.j[6 + b] = { imgA, Wt + 4ull * 4194304, bvi, Vti  + (size_t)b * 2048 * 288, 257, 1, 288 };
  }
  gemm_k<<<dim3(4, 16, 8), 256, 0, stream>>>(jc);

  rmsnorm_k<<<8192, 256, 0, stream>>>(Qb, gq);
  rmsnorm_k<<<1024, 256, 0, stream>>>(Ktxt, gk);
  rmsnorm_k<<<576, 256, 0, stream>>>(Kimg, gki);

  attn_k<<<dim3(64, 16, 2), 256, 0, stream>>>(Qb, Ktxt, Vtt, Kimg, Vti, lens, attn_o);

  GemmJobs jo = {};
  jo.j[0] = { attn_o, Wt + 5ull * 4194304, bo, out, 8192, 2, 2048 };
  gemm_k<<<dim3(64, 16, 1), 256, 0, stream>>>(jo);
}